// Round 11
// baseline (250.759 us; speedup 1.0000x reference)
//
#include <hip/hip_runtime.h>
#include <hip/hip_bf16.h>

#define N_NODES 20000
#define N_EDGES 320000
#define F_IN    128
#define F_HID   32
#define NHEAD   8
#define FDIM    256   // NHEAD * D (layer-1 feat width)
#define CAP     96    // max in-degree capacity; P(Poisson(16) > 96) ~ 1e-44

typedef __hip_bfloat16 bf16;
typedef __attribute__((ext_vector_type(8))) short short8;
typedef __attribute__((ext_vector_type(4))) float f32x4;

// bf16 round-to-nearest-even on raw bits
__device__ __forceinline__ unsigned short f2bf_rne(float f){
  unsigned u = __float_as_uint(f);
  unsigned r = u + 0x7FFFu + ((u >> 16) & 1u);
  return (unsigned short)(r >> 16);
}
__device__ __forceinline__ float bf2f(unsigned short s){
  return __uint_as_float((unsigned)s << 16);
}

// ---------------- fused prep ----------------
// blocks [0, FILLB)           : scatter edges into per-dst buckets
// blocks [FILLB, +128)        : W1 -> transposed bf16 hi/lo split (for MFMA gemm1)
// blocks [FILLB+128, +32)     : W2 -> W2t[c][k] fp32 transpose (edge2 epilogue)
// block  FILLB+160            : q_lt/q_rt[k][h] = column-projections of W2 by al2/ar2
#define FILLB  ((N_EDGES + 255) / 256)
__global__ void prep_kernel(const int* __restrict__ src, const int* __restrict__ dst,
                            int* __restrict__ cnt, int* __restrict__ bucket,
                            const float* __restrict__ W1, const float* __restrict__ W2,
                            const float* __restrict__ al2, const float* __restrict__ ar2,
                            unsigned short* __restrict__ h1, unsigned short* __restrict__ l1,
                            float* __restrict__ W2t, float* __restrict__ q_lt,
                            float* __restrict__ q_rt){
  const int b = blockIdx.x;
  if (b < FILLB){
    int i = b*256 + threadIdx.x;
    if (i < N_EDGES){
      int d = dst[i];
      int p = atomicAdd(&cnt[d], 1);
      if (p < CAP) bucket[(size_t)d*CAP + p] = src[i];
    }
  } else if (b < FILLB + 128){
    int i = (b - FILLB)*256 + threadIdx.x;   // over FDIM*F_IN
    int n = i >> 7, k = i & 127;
    float v = W1[(size_t)k*FDIM + n];
    unsigned short hs = f2bf_rne(v);
    h1[i] = hs;
    l1[i] = f2bf_rne(v - bf2f(hs));
  } else if (b < FILLB + 160){
    int i = (b - FILLB - 128)*256 + threadIdx.x;  // over 256*32
    int c = i >> 5, k = i & 31;
    W2t[i] = W2[(size_t)k*FDIM + c];
  } else {
    int t = threadIdx.x;            // t = k*8 + hh
    int k = t >> 3, hh = t & 7;
    float sl = 0.f, sr = 0.f;
    #pragma unroll
    for (int d = 0; d < 32; d++){
      float w = W2[(size_t)k*FDIM + hh*32 + d];
      sl = fmaf(w, al2[hh*32 + d], sl);
      sr = fmaf(w, ar2[hh*32 + d], sr);
    }
    q_lt[t] = sl;   // layout [k][hh]
    q_rt[t] = sr;
  }
}

// ---------------- MFMA GEMM: feat = X @ W1 (bf16x3 split) + el1/er1 ----------------
// Block = 256 thr = 4 waves; 16 rows x 256 cols. X fp32, split in-register.
// bf16x3: D += Ah*Bh + Ah*Bl + Al*Bh (lo*lo dropped, ~2^-18 rel err).
// C layout (m89): row=quad*4+r, col=lane&15.
template<int K>
__global__ __launch_bounds__(256) void gemm_mfma_kernel(
    const float* __restrict__ X,
    const unsigned short* __restrict__ Wthi, const unsigned short* __restrict__ Wtlo,
    const float* __restrict__ al, const float* __restrict__ ar,
    unsigned short* __restrict__ feat, float* __restrict__ el, float* __restrict__ er)
{
  const int tid  = threadIdx.x;
  const int wv   = tid >> 6;
  const int lane = tid & 63;
  const int quad = lane >> 4;
  const int l16  = lane & 15;
  const int m0   = blockIdx.x * 16;
  constexpr int NC = K / 32;

  short8 Ah[NC], Al_[NC];
  {
    const float* xrow = X + (size_t)(m0 + l16)*K;
    #pragma unroll
    for (int c = 0; c < NC; c++){
      float4 a0 = *(const float4*)(xrow + c*32 + quad*8);
      float4 a1 = *(const float4*)(xrow + c*32 + quad*8 + 4);
      const float vs[8] = {a0.x,a0.y,a0.z,a0.w,a1.x,a1.y,a1.z,a1.w};
      #pragma unroll
      for (int j = 0; j < 8; j++){
        unsigned short hs = f2bf_rne(vs[j]);
        Ah[c][j]  = (short)hs;
        Al_[c][j] = (short)f2bf_rne(vs[j] - bf2f(hs));
      }
    }
  }

  float elp[8], erp[8];   // [r*2 + hloc], hloc = tile>>1
  #pragma unroll
  for (int j = 0; j < 8; j++){ elp[j] = 0.f; erp[j] = 0.f; }

  #pragma unroll
  for (int t = 0; t < 4; t++){
    const int nc = wv*64 + t*16;
    const size_t brow = (size_t)(nc + l16) * K;
    f32x4 acc = {0.f, 0.f, 0.f, 0.f};
    #pragma unroll
    for (int c = 0; c < NC; c++){
      short8 Bh = *(const short8*)(Wthi + brow + c*32 + quad*8);
      short8 Bl = *(const short8*)(Wtlo + brow + c*32 + quad*8);
      acc = __builtin_amdgcn_mfma_f32_16x16x32_bf16(Ah[c],  Bh, acc, 0, 0, 0);
      acc = __builtin_amdgcn_mfma_f32_16x16x32_bf16(Ah[c],  Bl, acc, 0, 0, 0);
      acc = __builtin_amdgcn_mfma_f32_16x16x32_bf16(Al_[c], Bh, acc, 0, 0, 0);
    }
    const float alv = al[nc + l16];
    const float arv = ar[nc + l16];
    const int hl = t >> 1;
    #pragma unroll
    for (int r = 0; r < 4; r++){
      float v = acc[r];
      feat[(size_t)(m0 + quad*4 + r)*FDIM + nc + l16] = f2bf_rne(v);
      elp[r*2 + hl] = fmaf(v, alv, elp[r*2 + hl]);
      erp[r*2 + hl] = fmaf(v, arv, erp[r*2 + hl]);
    }
  }

  #pragma unroll
  for (int off = 1; off <= 8; off <<= 1){
    #pragma unroll
    for (int j = 0; j < 8; j++){
      elp[j] += __shfl_xor(elp[j], off);
      erp[j] += __shfl_xor(erp[j], off);
    }
  }
  __shared__ float el_lds[16][8], er_lds[16][8];
  if (l16 == 0){
    #pragma unroll
    for (int r = 0; r < 4; r++){
      #pragma unroll
      for (int hl = 0; hl < 2; hl++){
        el_lds[quad*4 + r][wv*2 + hl] = elp[r*2 + hl];
        er_lds[quad*4 + r][wv*2 + hl] = erp[r*2 + hl];
      }
    }
  }
  __syncthreads();
  if (tid < 128){
    int row = tid >> 3, h = tid & 7;
    el[(size_t)(m0 + row)*NHEAD + h] = el_lds[row][h];
    er[(size_t)(m0 + row)*NHEAD + h] = er_lds[row][h];
  }
}

// ---------------- layer-1 edge softmax + aggregate ----------------
// WAVE-PER-NODE, zero __syncthreads. Phase B gathers bf16 feat rows (512 B).
// Epilogue: h[n] = relu-mean; stores h as bf16 AND el2/er2 = h.q_l / h.q_r
// (algebraic fold of layer-2's logit projection — W2 never touches h here).
__global__ __launch_bounds__(256) void edge_agg_l1(
    const bf16* __restrict__ feat, const float* __restrict__ el,
    const float* __restrict__ er, const int* __restrict__ cnt,
    const int* __restrict__ bucket, const float* __restrict__ bias,
    const float* __restrict__ q_lt, const float* __restrict__ q_rt,
    unsigned short* __restrict__ h_out, float* __restrict__ el2,
    float* __restrict__ er2)
{
  const int tid  = threadIdx.x;
  const int wv   = tid >> 6;
  const int lane = tid & 63;
  const int n    = blockIdx.x*4 + wv;

  __shared__ float t_all[4][CAP*9];   // stride 9: conflict-free
  __shared__ int   s_all[4][CAP];
  __shared__ float sum_all[4][NHEAD];
  __shared__ float v_all[4][256];
  float* t_w = t_all[wv];
  int*   s_w = s_all[wv];

  int C = cnt[n];
  if (C > CAP) C = CAP;

  const float4* er4 = (const float4*)(er + (size_t)n*NHEAD);
  float4 era = er4[0], erb = er4[1];
  const float erv[8] = {era.x, era.y, era.z, era.w, erb.x, erb.y, erb.z, erb.w};

  // ---- Phase A: logits, 2 lanes per edge ----
  for (int idx = lane; idx < C*2; idx += 64){
    const int e = idx >> 1, j = idx & 1;
    const int sidx = bucket[(size_t)n*CAP + e];
    if (j == 0) s_w[e] = sidx;
    float4 a = ((const float4*)(el + (size_t)sidx*NHEAD))[j];
    const float ev[4] = {a.x, a.y, a.z, a.w};
    #pragma unroll
    for (int hh = 0; hh < 4; hh++){
      float v = ev[hh] + erv[j*4 + hh];
      t_w[e*9 + j*4 + hh] = (v > 0.f) ? v : 0.2f*v;   // leaky_relu(0.2)
    }
  }
  // per-head max + exp + denominator: 8 lanes per head
  {
    const int h = lane >> 3, d = lane & 7;
    float lm = -INFINITY;
    for (int e = d; e < C; e += 8) lm = fmaxf(lm, t_w[e*9 + h]);
    #pragma unroll
    for (int off = 4; off >= 1; off >>= 1) lm = fmaxf(lm, __shfl_xor(lm, off));
    float ls = 0.f;
    for (int e = d; e < C; e += 8){
      float ex = __expf(t_w[e*9 + h] - lm);
      t_w[e*9 + h] = ex;
      ls += ex;
    }
    #pragma unroll
    for (int off = 4; off >= 1; off >>= 1) ls += __shfl_xor(ls, off);
    if (d == 0) sum_all[wv][h] = ls;
  }

  // ---- Phase B: pipelined bf16 feat gathers, half-wave per edge ----
  const int sub = lane >> 5;
  const int l   = lane & 31;
  const int hB  = l >> 2;
  const int coff = l << 3;
  float acc[8] = {0,0,0,0,0,0,0,0};
  int e = sub;
  float4 fv;
  if (e < C) fv = *(const float4*)(feat + (size_t)s_w[e]*FDIM + coff);
  while (e < C){
    const int en = e + 2;
    float4 fnext;
    if (en < C) fnext = *(const float4*)(feat + (size_t)s_w[en]*FDIM + coff);
    const float w = t_w[e*9 + hB];
    const unsigned* u = (const unsigned*)&fv;
    #pragma unroll
    for (int j = 0; j < 4; j++){
      float flo = __uint_as_float(u[j] << 16);
      float fhi = __uint_as_float(u[j] & 0xFFFF0000u);
      acc[2*j]   = fmaf(w, flo, acc[2*j]);
      acc[2*j+1] = fmaf(w, fhi, acc[2*j+1]);
    }
    fv = fnext;
    e = en;
  }
  #pragma unroll
  for (int j = 0; j < 8; j++) acc[j] += __shfl_xor(acc[j], 32);

  // ---- epilogue: divide, bias, relu, head-mean -> h; then el2/er2 dots ----
  if (lane < 32){
    const float s = sum_all[wv][l >> 2];
    const float4* b4 = (const float4*)(bias + coff);
    float4 ba = b4[0], bb = b4[1];
    float bv[8] = {ba.x, ba.y, ba.z, ba.w, bb.x, bb.y, bb.z, bb.w};
    float v[8];
    #pragma unroll
    for (int j = 0; j < 8; j++){
      float val = (C > 0) ? (acc[j] / s) : 0.f;
      val += bv[j];
      val = fmaxf(val, 0.f);          // relu (layer-1 inter-layer activation)
      v[j] = val;
    }
    float4* v4 = (float4*)&v_all[wv][coff];
    v4[0] = make_float4(v[0], v[1], v[2], v[3]);
    v4[1] = make_float4(v[4], v[5], v[6], v[7]);
  }
  if (lane < 32){
    float hsum = 0.f;
    #pragma unroll
    for (int hh = 0; hh < 8; hh++) hsum += v_all[wv][hh*32 + lane];
    hsum *= 0.125f;                   // h[n][lane], fp32
    h_out[(size_t)n*32 + lane] = f2bf_rne(hsum);

    // el2/er2: dot h with q columns (q layout [k][hh], row = 32 B)
    float4 qa0 = ((const float4*)(q_lt + lane*8))[0];
    float4 qa1 = ((const float4*)(q_lt + lane*8))[1];
    float4 qb0 = ((const float4*)(q_rt + lane*8))[0];
    float4 qb1 = ((const float4*)(q_rt + lane*8))[1];
    float pl[8] = {hsum*qa0.x, hsum*qa0.y, hsum*qa0.z, hsum*qa0.w,
                   hsum*qa1.x, hsum*qa1.y, hsum*qa1.z, hsum*qa1.w};
    float pr[8] = {hsum*qb0.x, hsum*qb0.y, hsum*qb0.z, hsum*qb0.w,
                   hsum*qb1.x, hsum*qb1.y, hsum*qb1.z, hsum*qb1.w};
    #pragma unroll
    for (int off = 1; off <= 16; off <<= 1){
      #pragma unroll
      for (int j = 0; j < 8; j++){
        pl[j] += __shfl_xor(pl[j], off);
        pr[j] += __shfl_xor(pr[j], off);
      }
    }
    if (l == 0){
      #pragma unroll
      for (int j = 0; j < 8; j++){
        el2[(size_t)n*NHEAD + j] = pl[j];
        er2[(size_t)n*NHEAD + j] = pr[j];
      }
    }
  }
}

// ---------------- layer-2 edge softmax + aggregate (feat2 never built) ----------------
// Phase B gathers 64 B h rows (8x less than feat2); A_h = sum alpha_h h[src].
// Epilogue: out = (1/8) sum_h (A_h/s_h) @ W2[:,h*32..] + (1/8) sum_h b2[h,:].
__global__ __launch_bounds__(256) void edge_agg_l2(
    const unsigned short* __restrict__ h_bf, const float* __restrict__ el2,
    const float* __restrict__ er2, const int* __restrict__ cnt,
    const int* __restrict__ bucket, const float* __restrict__ W2t,
    const float* __restrict__ b2, float* __restrict__ outp)
{
  const int tid  = threadIdx.x;
  const int wv   = tid >> 6;
  const int lane = tid & 63;
  const int n    = blockIdx.x*4 + wv;

  __shared__ float t_all[4][CAP*9];
  __shared__ int   s_all[4][CAP];
  __shared__ float sum_all[4][NHEAD];
  __shared__ float A_lds[4][8][33];   // +1 pad: conflict-free writes
  float* t_w = t_all[wv];
  int*   s_w = s_all[wv];

  int C = cnt[n];
  if (C > CAP) C = CAP;

  const float4* er4 = (const float4*)(er2 + (size_t)n*NHEAD);
  float4 era = er4[0], erb = er4[1];
  const float erv[8] = {era.x, era.y, era.z, era.w, erb.x, erb.y, erb.z, erb.w};

  // ---- Phase A: logits, 2 lanes per edge ----
  for (int idx = lane; idx < C*2; idx += 64){
    const int e = idx >> 1, j = idx & 1;
    const int sidx = bucket[(size_t)n*CAP + e];
    if (j == 0) s_w[e] = sidx;
    float4 a = ((const float4*)(el2 + (size_t)sidx*NHEAD))[j];
    const float ev[4] = {a.x, a.y, a.z, a.w};
    #pragma unroll
    for (int hh = 0; hh < 4; hh++){
      float v = ev[hh] + erv[j*4 + hh];
      t_w[e*9 + j*4 + hh] = (v > 0.f) ? v : 0.2f*v;
    }
  }
  // per-head max + exp + denominator
  {
    const int h = lane >> 3, d = lane & 7;
    float lm = -INFINITY;
    for (int e = d; e < C; e += 8) lm = fmaxf(lm, t_w[e*9 + h]);
    #pragma unroll
    for (int off = 4; off >= 1; off >>= 1) lm = fmaxf(lm, __shfl_xor(lm, off));
    float ls = 0.f;
    for (int e = d; e < C; e += 8){
      float ex = __expf(t_w[e*9 + h] - lm);
      t_w[e*9 + h] = ex;
      ls += ex;
    }
    #pragma unroll
    for (int off = 4; off >= 1; off >>= 1) ls += __shfl_xor(ls, off);
    if (d == 0) sum_all[wv][h] = ls;
  }

  // ---- Phase B: A[h][dg*4..+3] += alpha_h * h[src], 64 B/edge gather ----
  const int h  = lane & 7;
  const int dg = lane >> 3;
  float A0=0.f, A1=0.f, A2=0.f, A3=0.f;
  int e = 0;
  ushort4 hv;
  if (e < C) hv = *(const ushort4*)(h_bf + (size_t)s_w[e]*32 + dg*4);
  while (e < C){
    const int en = e + 1;
    ushort4 hnext;
    if (en < C) hnext = *(const ushort4*)(h_bf + (size_t)s_w[en]*32 + dg*4);
    const float w = t_w[e*9 + h];
    A0 = fmaf(w, bf2f(hv.x), A0);
    A1 = fmaf(w, bf2f(hv.y), A1);
    A2 = fmaf(w, bf2f(hv.z), A2);
    A3 = fmaf(w, bf2f(hv.w), A3);
    hv = hnext;
    e = en;
  }
  {
    const float s = sum_all[wv][h];
    const float inv = (C > 0) ? (1.f / s) : 0.f;
    A_lds[wv][h][dg*4 + 0] = A0 * inv;
    A_lds[wv][h][dg*4 + 1] = A1 * inv;
    A_lds[wv][h][dg*4 + 2] = A2 * inv;
    A_lds[wv][h][dg*4 + 3] = A3 * inv;
  }

  // ---- epilogue: out[d] = (1/8) sum_h A_h . W2t[h*32+d][:] + bias-mean ----
  const int d  = lane & 31;
  const int hw = lane >> 5;
  float o = 0.f;
  #pragma unroll
  for (int h4 = 0; h4 < 4; h4++){
    const int hh = hw*4 + h4;
    const float* wrow = W2t + (size_t)(hh*32 + d)*32;   // 128 B contiguous
    #pragma unroll
    for (int k4 = 0; k4 < 8; k4++){
      float4 w4 = ((const float4*)wrow)[k4];
      o = fmaf(w4.x, A_lds[wv][hh][k4*4 + 0], o);
      o = fmaf(w4.y, A_lds[wv][hh][k4*4 + 1], o);
      o = fmaf(w4.z, A_lds[wv][hh][k4*4 + 2], o);
      o = fmaf(w4.w, A_lds[wv][hh][k4*4 + 3], o);
    }
  }
  o += __shfl_xor(o, 32);   // fold the two head-halves
  if (lane < 32){
    float bm = 0.f;
    #pragma unroll
    for (int hh = 0; hh < 8; hh++) bm += b2[hh*32 + d];
    outp[(size_t)n*32 + d] = (o + bm) * 0.125f;
  }
}

extern "C" void kernel_launch(void* const* d_in, const int* in_sizes, int n_in,
                              void* d_out, int out_size, void* d_ws, size_t ws_size,
                              hipStream_t stream)
{
  const float* x   = (const float*)d_in[0];
  const int*   src = (const int*)  d_in[1];
  const int*   dst = (const int*)  d_in[2];
  const float* W1  = (const float*)d_in[3];
  const float* al1 = (const float*)d_in[4];
  const float* ar1 = (const float*)d_in[5];
  const float* b1  = (const float*)d_in[6];
  const float* W2  = (const float*)d_in[7];
  const float* al2 = (const float*)d_in[8];
  const float* ar2 = (const float*)d_in[9];
  const float* b2  = (const float*)d_in[10];
  (void)in_sizes; (void)n_in; (void)out_size; (void)ws_size;

  size_t o = 0;
  char* base = (char*)d_ws;
  auto take = [&](size_t bytes) -> char* {
    char* p = base + o;
    o += (bytes + 255) & ~(size_t)255;
    return p;
  };
  unsigned short* feat  = (unsigned short*)take((size_t)N_NODES*FDIM*2);
  float* el1    = (float*)take((size_t)N_NODES*NHEAD*4);
  float* er1    = (float*)take((size_t)N_NODES*NHEAD*4);
  float* el2    = (float*)take((size_t)N_NODES*NHEAD*4);
  float* er2    = (float*)take((size_t)N_NODES*NHEAD*4);
  int*   cnt    = (int*)  take((size_t)N_NODES*4);
  int*   bucket = (int*)  take((size_t)N_NODES*CAP*4);
  unsigned short* hbf  = (unsigned short*)take((size_t)N_NODES*F_HID*2);
  unsigned short* W1th = (unsigned short*)take((size_t)FDIM*F_IN*2);
  unsigned short* W1tl = (unsigned short*)take((size_t)FDIM*F_IN*2);
  float* W2t    = (float*)take((size_t)FDIM*F_HID*4);
  float* q_lt   = (float*)take((size_t)F_HID*NHEAD*4);
  float* q_rt   = (float*)take((size_t)F_HID*NHEAD*4);

  hipMemsetAsync(cnt, 0, (size_t)N_NODES*4, stream);
  prep_kernel<<<FILLB + 161, 256, 0, stream>>>(
      src, dst, cnt, bucket, W1, W2, al2, ar2, W1th, W1tl, W2t, q_lt, q_rt);

  // layer 1
  gemm_mfma_kernel<F_IN><<<N_NODES/16, 256, 0, stream>>>(
      x, W1th, W1tl, al1, ar1, feat, el1, er1);
  edge_agg_l1<<<N_NODES/4, 256, 0, stream>>>(
      (const bf16*)feat, el1, er1, cnt, bucket, b1, q_lt, q_rt, hbf, el2, er2);

  // layer 2 (feat2 never materialized: aggregation commutes with W2)
  edge_agg_l2<<<N_NODES/4, 256, 0, stream>>>(
      hbf, el2, er2, cnt, bucket, W2t, b2, (float*)d_out);
}

// Round 12
// 197.113 us; speedup vs baseline: 1.2722x; 1.2722x over previous
//
#include <hip/hip_runtime.h>
#include <hip/hip_bf16.h>

#define N_NODES 20000
#define N_EDGES 320000
#define F_IN    128
#define F_HID   32
#define NHEAD   8
#define FDIM    256   // NHEAD * D (layer-1 feat width)
#define CAP     96    // max in-degree capacity; P(Poisson(16) > 96) ~ 1e-44

typedef __hip_bfloat16 bf16;
typedef __attribute__((ext_vector_type(8))) short short8;
typedef __attribute__((ext_vector_type(4))) float f32x4;

// bf16 round-to-nearest-even on raw bits
__device__ __forceinline__ unsigned short f2bf_rne(float f){
  unsigned u = __float_as_uint(f);
  unsigned r = u + 0x7FFFu + ((u >> 16) & 1u);
  return (unsigned short)(r >> 16);
}
__device__ __forceinline__ float bf2f(unsigned short s){
  return __uint_as_float((unsigned)s << 16);
}

// ---------------- fused prep ----------------
// blocks [0, FILLB)      : scatter edges into per-dst buckets
// blocks [FILLB, +128)   : W1 -> transposed bf16 hi/lo split (for MFMA gemm1)
// block  FILLB+128       : q_lt/q_rt[k][h] = column-projections of W2 by al2/ar2
#define FILLB  ((N_EDGES + 255) / 256)
__global__ void prep_kernel(const int* __restrict__ src, const int* __restrict__ dst,
                            int* __restrict__ cnt, int* __restrict__ bucket,
                            const float* __restrict__ W1, const float* __restrict__ W2,
                            const float* __restrict__ al2, const float* __restrict__ ar2,
                            unsigned short* __restrict__ h1, unsigned short* __restrict__ l1,
                            float* __restrict__ q_lt, float* __restrict__ q_rt){
  const int b = blockIdx.x;
  if (b < FILLB){
    int i = b*256 + threadIdx.x;
    if (i < N_EDGES){
      int d = dst[i];
      int p = atomicAdd(&cnt[d], 1);
      if (p < CAP) bucket[(size_t)d*CAP + p] = src[i];
    }
  } else if (b < FILLB + 128){
    int i = (b - FILLB)*256 + threadIdx.x;   // over FDIM*F_IN
    int n = i >> 7, k = i & 127;
    float v = W1[(size_t)k*FDIM + n];
    unsigned short hs = f2bf_rne(v);
    h1[i] = hs;
    l1[i] = f2bf_rne(v - bf2f(hs));
  } else {
    int t = threadIdx.x;            // t = k*8 + hh
    int k = t >> 3, hh = t & 7;
    float sl = 0.f, sr = 0.f;
    #pragma unroll
    for (int d = 0; d < 32; d++){
      float w = W2[(size_t)k*FDIM + hh*32 + d];
      sl = fmaf(w, al2[hh*32 + d], sl);
      sr = fmaf(w, ar2[hh*32 + d], sr);
    }
    q_lt[t] = sl;   // layout [k][hh]
    q_rt[t] = sr;
  }
}

// ---------------- MFMA GEMM: feat = X @ W1 (bf16x3 split) + el1/er1 ----------------
// Block = 256 thr = 4 waves; 16 rows x 256 cols. X fp32, split in-register.
// bf16x3: D += Ah*Bh + Ah*Bl + Al*Bh (lo*lo dropped, ~2^-18 rel err).
// C layout (m89): row=quad*4+r, col=lane&15.
template<int K>
__global__ __launch_bounds__(256) void gemm_mfma_kernel(
    const float* __restrict__ X,
    const unsigned short* __restrict__ Wthi, const unsigned short* __restrict__ Wtlo,
    const float* __restrict__ al, const float* __restrict__ ar,
    unsigned short* __restrict__ feat, float* __restrict__ el, float* __restrict__ er)
{
  const int tid  = threadIdx.x;
  const int wv   = tid >> 6;
  const int lane = tid & 63;
  const int quad = lane >> 4;
  const int l16  = lane & 15;
  const int m0   = blockIdx.x * 16;
  constexpr int NC = K / 32;

  short8 Ah[NC], Al_[NC];
  {
    const float* xrow = X + (size_t)(m0 + l16)*K;
    #pragma unroll
    for (int c = 0; c < NC; c++){
      float4 a0 = *(const float4*)(xrow + c*32 + quad*8);
      float4 a1 = *(const float4*)(xrow + c*32 + quad*8 + 4);
      const float vs[8] = {a0.x,a0.y,a0.z,a0.w,a1.x,a1.y,a1.z,a1.w};
      #pragma unroll
      for (int j = 0; j < 8; j++){
        unsigned short hs = f2bf_rne(vs[j]);
        Ah[c][j]  = (short)hs;
        Al_[c][j] = (short)f2bf_rne(vs[j] - bf2f(hs));
      }
    }
  }

  float elp[8], erp[8];   // [r*2 + hloc], hloc = tile>>1
  #pragma unroll
  for (int j = 0; j < 8; j++){ elp[j] = 0.f; erp[j] = 0.f; }

  #pragma unroll
  for (int t = 0; t < 4; t++){
    const int nc = wv*64 + t*16;
    const size_t brow = (size_t)(nc + l16) * K;
    f32x4 acc = {0.f, 0.f, 0.f, 0.f};
    #pragma unroll
    for (int c = 0; c < NC; c++){
      short8 Bh = *(const short8*)(Wthi + brow + c*32 + quad*8);
      short8 Bl = *(const short8*)(Wtlo + brow + c*32 + quad*8);
      acc = __builtin_amdgcn_mfma_f32_16x16x32_bf16(Ah[c],  Bh, acc, 0, 0, 0);
      acc = __builtin_amdgcn_mfma_f32_16x16x32_bf16(Ah[c],  Bl, acc, 0, 0, 0);
      acc = __builtin_amdgcn_mfma_f32_16x16x32_bf16(Al_[c], Bh, acc, 0, 0, 0);
    }
    const float alv = al[nc + l16];
    const float arv = ar[nc + l16];
    const int hl = t >> 1;
    #pragma unroll
    for (int r = 0; r < 4; r++){
      float v = acc[r];
      feat[(size_t)(m0 + quad*4 + r)*FDIM + nc + l16] = f2bf_rne(v);
      elp[r*2 + hl] = fmaf(v, alv, elp[r*2 + hl]);
      erp[r*2 + hl] = fmaf(v, arv, erp[r*2 + hl]);
    }
  }

  #pragma unroll
  for (int off = 1; off <= 8; off <<= 1){
    #pragma unroll
    for (int j = 0; j < 8; j++){
      elp[j] += __shfl_xor(elp[j], off);
      erp[j] += __shfl_xor(erp[j], off);
    }
  }
  __shared__ float el_lds[16][8], er_lds[16][8];
  if (l16 == 0){
    #pragma unroll
    for (int r = 0; r < 4; r++){
      #pragma unroll
      for (int hl = 0; hl < 2; hl++){
        el_lds[quad*4 + r][wv*2 + hl] = elp[r*2 + hl];
        er_lds[quad*4 + r][wv*2 + hl] = erp[r*2 + hl];
      }
    }
  }
  __syncthreads();
  if (tid < 128){
    int row = tid >> 3, h = tid & 7;
    el[(size_t)(m0 + row)*NHEAD + h] = el_lds[row][h];
    er[(size_t)(m0 + row)*NHEAD + h] = er_lds[row][h];
  }
}

// ---------------- layer-1 edge softmax + aggregate ----------------
// WAVE-PER-NODE, zero __syncthreads. Phase B gathers bf16 feat rows (512 B).
// Epilogue: h[n] = relu-mean; stores h as bf16 AND el2/er2 = h.q_l / h.q_r
// (algebraic fold of layer-2's logit projection).
__global__ __launch_bounds__(256) void edge_agg_l1(
    const bf16* __restrict__ feat, const float* __restrict__ el,
    const float* __restrict__ er, const int* __restrict__ cnt,
    const int* __restrict__ bucket, const float* __restrict__ bias,
    const float* __restrict__ q_lt, const float* __restrict__ q_rt,
    unsigned short* __restrict__ h_out, float* __restrict__ el2,
    float* __restrict__ er2)
{
  const int tid  = threadIdx.x;
  const int wv   = tid >> 6;
  const int lane = tid & 63;
  const int n    = blockIdx.x*4 + wv;

  __shared__ float t_all[4][CAP*9];   // stride 9: conflict-free
  __shared__ int   s_all[4][CAP];
  __shared__ float sum_all[4][NHEAD];
  __shared__ float v_all[4][256];
  float* t_w = t_all[wv];
  int*   s_w = s_all[wv];

  int C = cnt[n];
  if (C > CAP) C = CAP;

  const float4* er4 = (const float4*)(er + (size_t)n*NHEAD);
  float4 era = er4[0], erb = er4[1];
  const float erv[8] = {era.x, era.y, era.z, era.w, erb.x, erb.y, erb.z, erb.w};

  // ---- Phase A: logits, 2 lanes per edge ----
  for (int idx = lane; idx < C*2; idx += 64){
    const int e = idx >> 1, j = idx & 1;
    const int sidx = bucket[(size_t)n*CAP + e];
    if (j == 0) s_w[e] = sidx;
    float4 a = ((const float4*)(el + (size_t)sidx*NHEAD))[j];
    const float ev[4] = {a.x, a.y, a.z, a.w};
    #pragma unroll
    for (int hh = 0; hh < 4; hh++){
      float v = ev[hh] + erv[j*4 + hh];
      t_w[e*9 + j*4 + hh] = (v > 0.f) ? v : 0.2f*v;   // leaky_relu(0.2)
    }
  }
  // per-head max + exp + denominator: 8 lanes per head
  {
    const int h = lane >> 3, d = lane & 7;
    float lm = -INFINITY;
    for (int e = d; e < C; e += 8) lm = fmaxf(lm, t_w[e*9 + h]);
    #pragma unroll
    for (int off = 4; off >= 1; off >>= 1) lm = fmaxf(lm, __shfl_xor(lm, off));
    float ls = 0.f;
    for (int e = d; e < C; e += 8){
      float ex = __expf(t_w[e*9 + h] - lm);
      t_w[e*9 + h] = ex;
      ls += ex;
    }
    #pragma unroll
    for (int off = 4; off >= 1; off >>= 1) ls += __shfl_xor(ls, off);
    if (d == 0) sum_all[wv][h] = ls;
  }

  // ---- Phase B: pipelined bf16 feat gathers, half-wave per edge ----
  const int sub = lane >> 5;
  const int l   = lane & 31;
  const int hB  = l >> 2;
  const int coff = l << 3;
  float acc[8] = {0,0,0,0,0,0,0,0};
  int e = sub;
  float4 fv;
  if (e < C) fv = *(const float4*)(feat + (size_t)s_w[e]*FDIM + coff);
  while (e < C){
    const int en = e + 2;
    float4 fnext;
    if (en < C) fnext = *(const float4*)(feat + (size_t)s_w[en]*FDIM + coff);
    const float w = t_w[e*9 + hB];
    const unsigned* u = (const unsigned*)&fv;
    #pragma unroll
    for (int j = 0; j < 4; j++){
      float flo = __uint_as_float(u[j] << 16);
      float fhi = __uint_as_float(u[j] & 0xFFFF0000u);
      acc[2*j]   = fmaf(w, flo, acc[2*j]);
      acc[2*j+1] = fmaf(w, fhi, acc[2*j+1]);
    }
    fv = fnext;
    e = en;
  }
  #pragma unroll
  for (int j = 0; j < 8; j++) acc[j] += __shfl_xor(acc[j], 32);

  // ---- epilogue: divide, bias, relu, head-mean -> h; then el2/er2 dots ----
  if (lane < 32){
    const float s = sum_all[wv][l >> 2];
    const float4* b4 = (const float4*)(bias + coff);
    float4 ba = b4[0], bb = b4[1];
    float bv[8] = {ba.x, ba.y, ba.z, ba.w, bb.x, bb.y, bb.z, bb.w};
    float v[8];
    #pragma unroll
    for (int j = 0; j < 8; j++){
      float val = (C > 0) ? (acc[j] / s) : 0.f;
      val += bv[j];
      val = fmaxf(val, 0.f);          // relu (inter-layer activation)
      v[j] = val;
    }
    float4* v4 = (float4*)&v_all[wv][coff];
    v4[0] = make_float4(v[0], v[1], v[2], v[3]);
    v4[1] = make_float4(v[4], v[5], v[6], v[7]);
  }
  if (lane < 32){
    float hsum = 0.f;
    #pragma unroll
    for (int hh = 0; hh < 8; hh++) hsum += v_all[wv][hh*32 + lane];
    hsum *= 0.125f;                   // h[n][lane], fp32
    h_out[(size_t)n*32 + lane] = f2bf_rne(hsum);

    // el2/er2: dot h with q columns (q layout [k][hh], row = 32 B)
    float4 qa0 = ((const float4*)(q_lt + lane*8))[0];
    float4 qa1 = ((const float4*)(q_lt + lane*8))[1];
    float4 qb0 = ((const float4*)(q_rt + lane*8))[0];
    float4 qb1 = ((const float4*)(q_rt + lane*8))[1];
    float pl[8] = {hsum*qa0.x, hsum*qa0.y, hsum*qa0.z, hsum*qa0.w,
                   hsum*qa1.x, hsum*qa1.y, hsum*qa1.z, hsum*qa1.w};
    float pr[8] = {hsum*qb0.x, hsum*qb0.y, hsum*qb0.z, hsum*qb0.w,
                   hsum*qb1.x, hsum*qb1.y, hsum*qb1.z, hsum*qb1.w};
    #pragma unroll
    for (int off = 1; off <= 16; off <<= 1){
      #pragma unroll
      for (int j = 0; j < 8; j++){
        pl[j] += __shfl_xor(pl[j], off);
        pr[j] += __shfl_xor(pr[j], off);
      }
    }
    if (l == 0){
      #pragma unroll
      for (int j = 0; j < 8; j++){
        el2[(size_t)n*NHEAD + j] = pl[j];
        er2[(size_t)n*NHEAD + j] = pr[j];
      }
    }
  }
}

// ---------------- layer-2 edge softmax + aggregate (feat2 never built) ----------------
// Phase B gathers 64 B h rows; A_h = (1/s_h) sum alpha_h h[src] into LDS.
// Epilogue is BLOCK-COOPERATIVE (round-11 lesson: per-wave full-W2 epilogue
// read 640 MB at 128B lane stride — 96 us). Thread tid owns column c=h*32+d;
// W2[k][c] loads are coalesced 1KB/k per block, amortized over 4 nodes.
__global__ __launch_bounds__(256) void edge_agg_l2(
    const unsigned short* __restrict__ h_bf, const float* __restrict__ el2,
    const float* __restrict__ er2, const int* __restrict__ cnt,
    const int* __restrict__ bucket, const float* __restrict__ W2,
    const float* __restrict__ b2, float* __restrict__ outp)
{
  const int tid  = threadIdx.x;
  const int wv   = tid >> 6;
  const int lane = tid & 63;
  const int n    = blockIdx.x*4 + wv;

  __shared__ float t_all[4][CAP*9];
  __shared__ int   s_all[4][CAP];
  __shared__ float sum_all[4][NHEAD];
  __shared__ float A_lds[4][NHEAD][33];   // +1 pad: ~2-way max on writes
  __shared__ float red[4][256];
  float* t_w = t_all[wv];
  int*   s_w = s_all[wv];

  int C = cnt[n];
  if (C > CAP) C = CAP;

  const float4* er4 = (const float4*)(er2 + (size_t)n*NHEAD);
  float4 era = er4[0], erb = er4[1];
  const float erv[8] = {era.x, era.y, era.z, era.w, erb.x, erb.y, erb.z, erb.w};

  // ---- Phase A: logits, 2 lanes per edge ----
  for (int idx = lane; idx < C*2; idx += 64){
    const int e = idx >> 1, j = idx & 1;
    const int sidx = bucket[(size_t)n*CAP + e];
    if (j == 0) s_w[e] = sidx;
    float4 a = ((const float4*)(el2 + (size_t)sidx*NHEAD))[j];
    const float ev[4] = {a.x, a.y, a.z, a.w};
    #pragma unroll
    for (int hh = 0; hh < 4; hh++){
      float v = ev[hh] + erv[j*4 + hh];
      t_w[e*9 + j*4 + hh] = (v > 0.f) ? v : 0.2f*v;
    }
  }
  // per-head max + exp + denominator
  {
    const int h = lane >> 3, d = lane & 7;
    float lm = -INFINITY;
    for (int e = d; e < C; e += 8) lm = fmaxf(lm, t_w[e*9 + h]);
    #pragma unroll
    for (int off = 4; off >= 1; off >>= 1) lm = fmaxf(lm, __shfl_xor(lm, off));
    float ls = 0.f;
    for (int e = d; e < C; e += 8){
      float ex = __expf(t_w[e*9 + h] - lm);
      t_w[e*9 + h] = ex;
      ls += ex;
    }
    #pragma unroll
    for (int off = 4; off >= 1; off >>= 1) ls += __shfl_xor(ls, off);
    if (d == 0) sum_all[wv][h] = ls;
  }

  // ---- Phase B: A[h][dg*4..+3] += alpha_h * h[src], 64 B/edge gather ----
  const int h  = lane & 7;
  const int dg = lane >> 3;
  float A0=0.f, A1=0.f, A2=0.f, A3=0.f;
  int e = 0;
  ushort4 hv;
  if (e < C) hv = *(const ushort4*)(h_bf + (size_t)s_w[e]*32 + dg*4);
  while (e < C){
    const int en = e + 1;
    ushort4 hnext;
    if (en < C) hnext = *(const ushort4*)(h_bf + (size_t)s_w[en]*32 + dg*4);
    const float w = t_w[e*9 + h];
    A0 = fmaf(w, bf2f(hv.x), A0);
    A1 = fmaf(w, bf2f(hv.y), A1);
    A2 = fmaf(w, bf2f(hv.z), A2);
    A3 = fmaf(w, bf2f(hv.w), A3);
    hv = hnext;
    e = en;
  }
  {
    const float s = sum_all[wv][h];
    const float inv = (C > 0) ? (1.f / s) : 0.f;
    A_lds[wv][h][dg*4 + 0] = A0 * inv;
    A_lds[wv][h][dg*4 + 1] = A1 * inv;
    A_lds[wv][h][dg*4 + 2] = A2 * inv;
    A_lds[wv][h][dg*4 + 3] = A3 * inv;
  }
  __syncthreads();   // all 4 waves' A ready

  // ---- block-cooperative epilogue: c = tid = h*32+d; coalesced W2[k][c] ----
  {
    const int c  = tid;
    const int hc = c >> 5;
    float p0=0.f, p1=0.f, p2=0.f, p3=0.f;
    for (int k = 0; k < F_HID; k++){
      float w = W2[(size_t)k*FDIM + c];     // 1 KB coalesced per k per block
      p0 = fmaf(A_lds[0][hc][k], w, p0);    // LDS broadcast reads
      p1 = fmaf(A_lds[1][hc][k], w, p1);
      p2 = fmaf(A_lds[2][hc][k], w, p2);
      p3 = fmaf(A_lds[3][hc][k], w, p3);
    }
    red[0][c] = p0; red[1][c] = p1; red[2][c] = p2; red[3][c] = p3;
  }
  __syncthreads();
  if (tid < 128){
    const int nn = tid >> 5, d = tid & 31;
    float s = 0.f, bm = 0.f;
    #pragma unroll
    for (int hh = 0; hh < 8; hh++){
      s  += red[nn][hh*32 + d];
      bm += b2[hh*32 + d];
    }
    outp[(size_t)(blockIdx.x*4 + nn)*32 + d] = (s + bm) * 0.125f;
  }
}

extern "C" void kernel_launch(void* const* d_in, const int* in_sizes, int n_in,
                              void* d_out, int out_size, void* d_ws, size_t ws_size,
                              hipStream_t stream)
{
  const float* x   = (const float*)d_in[0];
  const int*   src = (const int*)  d_in[1];
  const int*   dst = (const int*)  d_in[2];
  const float* W1  = (const float*)d_in[3];
  const float* al1 = (const float*)d_in[4];
  const float* ar1 = (const float*)d_in[5];
  const float* b1  = (const float*)d_in[6];
  const float* W2  = (const float*)d_in[7];
  const float* al2 = (const float*)d_in[8];
  const float* ar2 = (const float*)d_in[9];
  const float* b2  = (const float*)d_in[10];
  (void)in_sizes; (void)n_in; (void)out_size; (void)ws_size;

  size_t o = 0;
  char* base = (char*)d_ws;
  auto take = [&](size_t bytes) -> char* {
    char* p = base + o;
    o += (bytes + 255) & ~(size_t)255;
    return p;
  };
  unsigned short* feat  = (unsigned short*)take((size_t)N_NODES*FDIM*2);
  float* el1    = (float*)take((size_t)N_NODES*NHEAD*4);
  float* er1    = (float*)take((size_t)N_NODES*NHEAD*4);
  float* el2    = (float*)take((size_t)N_NODES*NHEAD*4);
  float* er2    = (float*)take((size_t)N_NODES*NHEAD*4);
  int*   cnt    = (int*)  take((size_t)N_NODES*4);
  int*   bucket = (int*)  take((size_t)N_NODES*CAP*4);
  unsigned short* hbf  = (unsigned short*)take((size_t)N_NODES*F_HID*2);
  unsigned short* W1th = (unsigned short*)take((size_t)FDIM*F_IN*2);
  unsigned short* W1tl = (unsigned short*)take((size_t)FDIM*F_IN*2);
  float* q_lt   = (float*)take((size_t)F_HID*NHEAD*4);
  float* q_rt   = (float*)take((size_t)F_HID*NHEAD*4);

  hipMemsetAsync(cnt, 0, (size_t)N_NODES*4, stream);
  prep_kernel<<<FILLB + 129, 256, 0, stream>>>(
      src, dst, cnt, bucket, W1, W2, al2, ar2, W1th, W1tl, q_lt, q_rt);

  // layer 1
  gemm_mfma_kernel<F_IN><<<N_NODES/16, 256, 0, stream>>>(
      x, W1th, W1tl, al1, ar1, feat, el1, er1);
  edge_agg_l1<<<N_NODES/4, 256, 0, stream>>>(
      (const bf16*)feat, el1, er1, cnt, bucket, b1, q_lt, q_rt, hbf, el2, er2);

  // layer 2 (feat2 never materialized; block-cooperative W2 epilogue)
  edge_agg_l2<<<N_NODES/4, 256, 0, stream>>>(
      hbf, el2, er2, cnt, bucket, W2, b2, (float*)d_out);
}